// Round 5
// baseline (65250.476 us; speedup 1.0000x reference)
//
#include <hip/hip_runtime.h>
#include <hip/hip_bf16.h>

typedef __hip_bfloat16 bf16_t;
typedef short bf16x8 __attribute__((ext_vector_type(8)));   // 8 bf16 bit patterns (4 VGPRs)
typedef float floatx4 __attribute__((ext_vector_type(4)));

#define B_SZ 128
#define T_SZ 1024
#define D_SZ 256
#define H_SZ 1024
#define O_SZ 10
#define G4H  (4 * H_SZ)     // 4096 gate columns
#define KTOT 1280           // H + D
#define NKK  40             // KTOT / 32 (MFMA K-steps)
#define NKH  32             // H / 32 (K-steps on the recurrent part)
#define COLS 16             // gate columns per WG (4 hidden units x 4 gates)
#define NWG  256            // one WG per CU
#define FLAG_STRIDE 32      // uints between per-block flags (128 B, own cacheline)

// Zero hbuf[0] (h_{-1} = 0) and the 256 barrier flags. Stream-ordered before
// lstm_main. d_ws is poisoned 0xAA by the harness.
__global__ void init_state(unsigned int* __restrict__ hz, unsigned int* __restrict__ flags) {
    int idx = blockIdx.x * 256 + threadIdx.x;   // 256 x 256 = 65536
    hz[idx] = 0u;                               // 65536 uints = hbuf[0] (128x1024 bf16)
    if (idx < NWG) flags[idx * FLAG_STRIDE] = 0u;
}

// Contention-free grid barrier: per-block flag (own cacheline), monotonic
// generation value. Arrival = 1 store/block (parallel across blocks); wait =
// thread j polls block j's flag (256 distinct lines, relaxed loads). One
// threadfence on each side provides agent-scope release/acquire.
__device__ __forceinline__ void grid_barrier(unsigned int* __restrict__ flags,
                                             unsigned int tgt) {
    __threadfence();    // release: this thread's h stores -> agent scope
    __syncthreads();    // all threads of block fenced
    if (threadIdx.x == 0)
        __hip_atomic_store(flags + blockIdx.x * FLAG_STRIDE, tgt,
                           __ATOMIC_RELAXED, __HIP_MEMORY_SCOPE_AGENT);
    unsigned int* w = flags + threadIdx.x * FLAG_STRIDE;
    while (__hip_atomic_load(w, __ATOMIC_RELAXED, __HIP_MEMORY_SCOPE_AGENT) < tgt)
        __builtin_amdgcn_s_sleep(2);
    __syncthreads();    // whole block has seen all 256 arrivals
    __threadfence();    // acquire: no stale h reads after this
}

// Convert 8 consecutive fp32 to a bf16x8 MFMA fragment (RNE via __float2bfloat16).
__device__ __forceinline__ bf16x8 cvt8(const float* __restrict__ p) {
    floatx4 a = *(const floatx4*)p;
    floatx4 b = *(const floatx4*)(p + 4);
    union { bf16_t h; short s; } u;
    bf16x8 r;
    u.h = __float2bfloat16(a[0]); r[0] = u.s;
    u.h = __float2bfloat16(a[1]); r[1] = u.s;
    u.h = __float2bfloat16(a[2]); r[2] = u.s;
    u.h = __float2bfloat16(a[3]); r[3] = u.s;
    u.h = __float2bfloat16(b[0]); r[4] = u.s;
    u.h = __float2bfloat16(b[1]); r[5] = u.s;
    u.h = __float2bfloat16(b[2]); r[6] = u.s;
    u.h = __float2bfloat16(b[3]); r[7] = u.s;
    return r;
}

// ---------------------------------------------------------------------------
// 256 WGs x 256 threads (1/CU). WG jg owns hidden units jg*4..jg*4+3 (16 gate
// columns) for all 128 batch rows, all 1024 steps. Weights (converted to bf16)
// stay in LDS; cell state c in registers; h exchanged as bf16 via a double
// buffer in d_ws with the flag-array grid barrier per step.
// ---------------------------------------------------------------------------
__global__ void __launch_bounds__(256, 1)
lstm_main(const float* __restrict__ x,      // [B][T][D] fp32
          const float* __restrict__ Wx,     // [D][4H]   fp32
          const float* __restrict__ Wh,     // [H][4H]   fp32
          const float* __restrict__ bias,   // [4H]      fp32
          bf16_t* __restrict__ hbuf,        // [2][128][1024] bf16 in d_ws
          unsigned int* __restrict__ flags) { // 256 x FLAG_STRIDE uints in d_ws
    // Wlds layout: [kk][c][q][j], k = kk*32 + q*8 + j, c = gate*4 + u (16 cols)
    __shared__ bf16_t Wlds[NKK * COLS * 32];   // 40 KB, resident all steps
    __shared__ float  G[B_SZ * COLS];          // 8 KB gate staging
    __shared__ float  sbias[COLS];

    const int tid  = threadIdx.x;
    const int jg   = blockIdx.x;
    const int lane = tid & 63;
    const int wave = tid >> 6;

    // ---- Stage this WG's weight slice into LDS (fp32 -> bf16). ----
    for (int k = tid; k < KTOT; k += 256) {
        int kk = k >> 5, q = (k >> 3) & 3, j = k & 7;
        bf16_t* dst = Wlds + kk * (COLS * 32) + q * 8 + j;
        const float* row = (k < H_SZ) ? (Wh + (size_t)k * G4H)
                                      : (Wx + (size_t)(k - H_SZ) * G4H);
        #pragma unroll
        for (int gate = 0; gate < 4; ++gate) {
            floatx4 w = *(const floatx4*)(row + gate * H_SZ + jg * 4);  // 16B aligned
            #pragma unroll
            for (int u = 0; u < 4; ++u)
                dst[(gate * 4 + u) * 32] = __float2bfloat16(w[u]);
        }
    }
    if (tid < COLS) {
        int gate = tid >> 2, u = tid & 3;
        sbias[tid] = bias[gate * H_SZ + jg * 4 + u];
    }
    __syncthreads();   // Wlds + sbias ready (hbuf[0] zeroed by init_state)

    float c0 = 0.f, c1 = 0.f;           // cell state, 2 cells per thread

    const int qk   = (lane >> 4) * 8;   // k-offset within 32 (A/B quad): 0/8/16/24
    const int cidx = lane & 15;         // N index within tile
    const int m0   = wave * 32 + (lane & 15);   // batch rows this lane feeds
    const int m1   = m0 + 16;
    const int bl   = tid >> 1;          // batch row for elementwise
    const int u0   = 2 * (tid & 1);     // hidden-unit pair within WG

    const bf16_t* bp = Wlds + cidx * 32 + qk;

    for (int t = 0; t < T_SZ; ++t) {
        const int rb = t & 1;
        const bf16_t* hsrc = hbuf + rb * (B_SZ * H_SZ);
        floatx4 acc0 = {0.f, 0.f, 0.f, 0.f};
        floatx4 acc1 = {0.f, 0.f, 0.f, 0.f};

        const bf16_t* a0p = hsrc + m0 * H_SZ + qk;
        const bf16_t* a1p = hsrc + m1 * H_SZ + qk;

        #pragma unroll 8
        for (int kk = 0; kk < NKH; ++kk) {      // h @ Wh part (K = 1024), h is bf16
            bf16x8 a0 = *(const bf16x8*)(a0p + kk * 32);
            bf16x8 a1 = *(const bf16x8*)(a1p + kk * 32);
            bf16x8 bb = *(const bf16x8*)(bp + kk * (COLS * 32));
            acc0 = __builtin_amdgcn_mfma_f32_16x16x32_bf16(a0, bb, acc0, 0, 0, 0);
            acc1 = __builtin_amdgcn_mfma_f32_16x16x32_bf16(a1, bb, acc1, 0, 0, 0);
        }
        // x_t @ Wx part (K = 256): x is fp32, convert per-fragment.
        const float* x0p = x + ((size_t)m0 * T_SZ + t) * D_SZ + qk;
        const float* x1p = x + ((size_t)m1 * T_SZ + t) * D_SZ + qk;
        #pragma unroll
        for (int kk = 0; kk < 8; ++kk) {
            bf16x8 a0 = cvt8(x0p + kk * 32);
            bf16x8 a1 = cvt8(x1p + kk * 32);
            bf16x8 bb = *(const bf16x8*)(bp + (NKH + kk) * (COLS * 32));
            acc0 = __builtin_amdgcn_mfma_f32_16x16x32_bf16(a0, bb, acc0, 0, 0, 0);
            acc1 = __builtin_amdgcn_mfma_f32_16x16x32_bf16(a1, bb, acc1, 0, 0, 0);
        }

        // C/D layout (m89-verified): col = lane&15, row = (lane>>4)*4 + reg.
        {
            int rowb = wave * 32 + (lane >> 4) * 4;
            #pragma unroll
            for (int r = 0; r < 4; ++r) {
                G[(rowb + r) * COLS + cidx]      = acc0[r];
                G[(rowb + 16 + r) * COLS + cidx] = acc1[r];
            }
        }
        __syncthreads();

        // Elementwise LSTM cell: thread owns cells (bl, u0) and (bl, u0+1).
        const int wb = rb ^ 1;
        bf16_t* hdst = hbuf + wb * (B_SZ * H_SZ);
        float hv[2];
        #pragma unroll
        for (int s = 0; s < 2; ++s) {
            int u = u0 + s;
            float gi = G[bl * COLS + u]      + sbias[u];
            float gf = G[bl * COLS + 4 + u]  + sbias[4 + u];
            float gg = G[bl * COLS + 8 + u]  + sbias[8 + u];
            float go = G[bl * COLS + 12 + u] + sbias[12 + u];
            float i_ = 1.f / (1.f + __expf(-gi));
            float f_ = 1.f / (1.f + __expf(-gf));
            float g_ = tanhf(gg);
            float o_ = 1.f / (1.f + __expf(-go));
            float cn = f_ * (s ? c1 : c0) + i_ * g_;
            if (s) c1 = cn; else c0 = cn;
            hv[s] = o_ * tanhf(cn);
        }
        union { unsigned int u32; bf16_t h2[2]; } pk;
        pk.h2[0] = __float2bfloat16(hv[0]);
        pk.h2[1] = __float2bfloat16(hv[1]);
        *(unsigned int*)(hdst + bl * H_SZ + jg * 4 + u0) = pk.u32;

        if (t != T_SZ - 1) grid_barrier(flags, (unsigned int)t + 1u);
    }
}

// out[128,10] = h_T @ Wd + bd. h_T (bf16) is in hbuf[0]; Wd/bd/out are fp32.
__global__ void decode(const bf16_t* __restrict__ h, const float* __restrict__ Wd,
                       const float* __restrict__ bd, float* __restrict__ out) {
    int b = blockIdx.x;
    int l = threadIdx.x;   // 64
    float acc[O_SZ] = {};
    for (int k = l; k < H_SZ; k += 64) {
        float hv = __bfloat162float(h[b * H_SZ + k]);
        #pragma unroll
        for (int o = 0; o < O_SZ; ++o)
            acc[o] += hv * Wd[k * O_SZ + o];
    }
    #pragma unroll
    for (int o = 0; o < O_SZ; ++o)
        #pragma unroll
        for (int off = 32; off; off >>= 1)
            acc[o] += __shfl_down(acc[o], off);
    if (l == 0)
        #pragma unroll
        for (int o = 0; o < O_SZ; ++o)
            out[b * O_SZ + o] = acc[o] + bd[o];
}

extern "C" void kernel_launch(void* const* d_in, const int* in_sizes, int n_in,
                              void* d_out, int out_size, void* d_ws, size_t ws_size,
                              hipStream_t stream) {
    const float* x  = (const float*)d_in[0];
    const float* Wx = (const float*)d_in[1];
    const float* Wh = (const float*)d_in[2];
    const float* bb = (const float*)d_in[3];
    const float* Wd = (const float*)d_in[4];
    const float* bd = (const float*)d_in[5];
    float* out = (float*)d_out;

    bf16_t* hbuf = (bf16_t*)d_ws;                         // [2][128][1024] = 512 KB
    unsigned int* flags = (unsigned int*)((char*)d_ws + 2 * B_SZ * H_SZ * sizeof(bf16_t));

    init_state<<<dim3(NWG), dim3(256), 0, stream>>>((unsigned int*)d_ws, flags);
    lstm_main<<<dim3(NWG), dim3(256), 0, stream>>>(x, Wx, Wh, bb, hbuf, flags);
    decode<<<dim3(B_SZ), dim3(64), 0, stream>>>(hbuf, Wd, bd, out);
}

// Round 6
// 14775.430 us; speedup vs baseline: 4.4161x; 4.4161x over previous
//
#include <hip/hip_runtime.h>
#include <hip/hip_bf16.h>

typedef __hip_bfloat16 bf16_t;
typedef short bf16x8 __attribute__((ext_vector_type(8)));   // 8 bf16 bit patterns (4 VGPRs)
typedef float floatx4 __attribute__((ext_vector_type(4)));

#define B_SZ 128
#define T_SZ 1024
#define D_SZ 256
#define H_SZ 1024
#define O_SZ 10
#define G4H  (4 * H_SZ)     // 4096 gate columns
#define KTOT 1280           // H + D
#define NKK  40             // KTOT / 32 (MFMA K-steps)
#define NKH  32             // H / 32 (K-steps on the recurrent part)
#define COLS 16             // gate columns per WG (4 hidden units x 4 gates)
#define NWG  256            // one WG per CU
#define FLAG_STRIDE 32      // uints between per-block flags (128 B, own cacheline)

// Zero hbuf[0] (h_{-1} = 0) and the 256 barrier flags. Kernel-end writeback
// pushes these to the coherence point before lstm_main starts.
__global__ void init_state(unsigned int* __restrict__ hz, unsigned int* __restrict__ flags) {
    int idx = blockIdx.x * 256 + threadIdx.x;   // 256 x 256 = 65536
    hz[idx] = 0u;                               // 65536 uints = hbuf[0] (128x1024 bf16)
    if (idx < NWG) flags[idx * FLAG_STRIDE] = 0u;
}

// Agent-coherent 16B load: bypasses (possibly stale) L1/L2, reads the MALL
// coherence point. No cache-maintenance side effects.
__device__ __forceinline__ bf16x8 load_h16(const bf16_t* p) {
    bf16x8 r;
    asm volatile("global_load_dwordx4 %0, %1, off sc0 sc1"
                 : "=v"(r) : "v"(p) : "memory");
    return r;
}
__device__ __forceinline__ void vmwait0() {
    asm volatile("s_waitcnt vmcnt(0)" ::: "memory");
}

// Grid barrier with NO cache-maintenance ops:
//   release = vmcnt(0) drain of this wave's sc1 h-stores (already at MALL),
//   arrival = one relaxed agent store to the block's own 128B-spaced flag,
//   wait    = thread j polls block j's flag (sc1 loads, 256 distinct lines).
// No acquire fence: subsequent h reads are themselves agent-coherent, and
// x/weights are read-only, so warm L2 lines are always valid.
__device__ __forceinline__ void grid_barrier(unsigned int* __restrict__ flags,
                                             unsigned int tgt) {
    vmwait0();          // this wave's h stores completed to coherence point
    __syncthreads();    // all waves of the block drained
    if (threadIdx.x == 0)
        __hip_atomic_store(flags + blockIdx.x * FLAG_STRIDE, tgt,
                           __ATOMIC_RELAXED, __HIP_MEMORY_SCOPE_AGENT);
    unsigned int* w = flags + threadIdx.x * FLAG_STRIDE;
    while (__hip_atomic_load(w, __ATOMIC_RELAXED, __HIP_MEMORY_SCOPE_AGENT) < tgt)
        __builtin_amdgcn_s_sleep(8);
    __syncthreads();    // whole block has observed all 256 arrivals
}

// Convert 8 consecutive fp32 to a bf16x8 MFMA fragment (RNE via __float2bfloat16).
__device__ __forceinline__ bf16x8 cvt8(const float* __restrict__ p) {
    floatx4 a = *(const floatx4*)p;
    floatx4 b = *(const floatx4*)(p + 4);
    union { bf16_t h; short s; } u;
    bf16x8 r;
    u.h = __float2bfloat16(a[0]); r[0] = u.s;
    u.h = __float2bfloat16(a[1]); r[1] = u.s;
    u.h = __float2bfloat16(a[2]); r[2] = u.s;
    u.h = __float2bfloat16(a[3]); r[3] = u.s;
    u.h = __float2bfloat16(b[0]); r[4] = u.s;
    u.h = __float2bfloat16(b[1]); r[5] = u.s;
    u.h = __float2bfloat16(b[2]); r[6] = u.s;
    u.h = __float2bfloat16(b[3]); r[7] = u.s;
    return r;
}

// ---------------------------------------------------------------------------
// 256 WGs x 256 threads (1/CU). WG jg owns hidden units jg*4..jg*4+3 (16 gate
// columns) for all 128 batch rows, all 1024 steps. Weights (bf16) stay in LDS;
// cell state c in registers; h exchanged as bf16 via a double buffer in d_ws.
// h traffic goes through agent-coherent (sc1) loads/stores; x and weights use
// normal cached loads and stay L2-warm (no fences ever invalidate L2).
// ---------------------------------------------------------------------------
__global__ void __launch_bounds__(256, 1)
lstm_main(const float* __restrict__ x,      // [B][T][D] fp32
          const float* __restrict__ Wx,     // [D][4H]   fp32
          const float* __restrict__ Wh,     // [H][4H]   fp32
          const float* __restrict__ bias,   // [4H]      fp32
          bf16_t* __restrict__ hbuf,        // [2][128][1024] bf16 in d_ws
          unsigned int* __restrict__ flags) { // 256 x FLAG_STRIDE uints in d_ws
    // Wlds layout: [kk][c][q][j], k = kk*32 + q*8 + j, c = gate*4 + u (16 cols)
    __shared__ bf16_t Wlds[NKK * COLS * 32];   // 40 KB, resident all steps
    __shared__ float  G[B_SZ * COLS];          // 8 KB gate staging
    __shared__ float  sbias[COLS];

    const int tid  = threadIdx.x;
    const int jg   = blockIdx.x;
    const int lane = tid & 63;
    const int wave = tid >> 6;

    // ---- Stage this WG's weight slice into LDS (fp32 -> bf16). ----
    for (int k = tid; k < KTOT; k += 256) {
        int kk = k >> 5, q = (k >> 3) & 3, j = k & 7;
        bf16_t* dst = Wlds + kk * (COLS * 32) + q * 8 + j;
        const float* row = (k < H_SZ) ? (Wh + (size_t)k * G4H)
                                      : (Wx + (size_t)(k - H_SZ) * G4H);
        #pragma unroll
        for (int gate = 0; gate < 4; ++gate) {
            floatx4 w = *(const floatx4*)(row + gate * H_SZ + jg * 4);  // 16B aligned
            #pragma unroll
            for (int u = 0; u < 4; ++u)
                dst[(gate * 4 + u) * 32] = __float2bfloat16(w[u]);
        }
    }
    if (tid < COLS) {
        int gate = tid >> 2, u = tid & 3;
        sbias[tid] = bias[gate * H_SZ + jg * 4 + u];
    }
    __syncthreads();   // Wlds + sbias ready (hbuf[0] zeroed by init_state)

    float c0 = 0.f, c1 = 0.f;           // cell state, 2 cells per thread

    const int qk   = (lane >> 4) * 8;   // k-offset within 32 (A/B quad): 0/8/16/24
    const int cidx = lane & 15;         // N index within tile
    const int m0   = wave * 32 + (lane & 15);   // batch rows this lane feeds
    const int m1   = m0 + 16;
    const int bl   = tid >> 1;          // batch row for elementwise
    const int u0   = 2 * (tid & 1);     // hidden-unit pair within WG

    const bf16_t* bp = Wlds + cidx * 32 + qk;

    for (int t = 0; t < T_SZ; ++t) {
        const int rb = t & 1;
        const bf16_t* hsrc = hbuf + rb * (B_SZ * H_SZ);
        floatx4 acc0 = {0.f, 0.f, 0.f, 0.f};
        floatx4 acc1 = {0.f, 0.f, 0.f, 0.f};

        const bf16_t* a0p = hsrc + m0 * H_SZ + qk;
        const bf16_t* a1p = hsrc + m1 * H_SZ + qk;

        // h @ Wh (K=1024): agent-coherent loads, 16 fragments (16 KB/wave) in
        // flight per chunk before one vmcnt(0) -> deep MLP against MALL latency.
        #pragma unroll
        for (int ch = 0; ch < 4; ++ch) {
            bf16x8 f0[8], f1[8];
            #pragma unroll
            for (int kk = 0; kk < 8; ++kk) {
                f0[kk] = load_h16(a0p + (ch * 8 + kk) * 32);
                f1[kk] = load_h16(a1p + (ch * 8 + kk) * 32);
            }
            vmwait0();
            #pragma unroll
            for (int kk = 0; kk < 8; ++kk) {
                bf16x8 bb = *(const bf16x8*)(bp + (ch * 8 + kk) * (COLS * 32));
                acc0 = __builtin_amdgcn_mfma_f32_16x16x32_bf16(f0[kk], bb, acc0, 0, 0, 0);
                acc1 = __builtin_amdgcn_mfma_f32_16x16x32_bf16(f1[kk], bb, acc1, 0, 0, 0);
            }
        }

        // x_t @ Wx (K=256): x is read-only fp32, normal cached loads (L2-warm).
        const float* x0p = x + ((size_t)m0 * T_SZ + t) * D_SZ + qk;
        const float* x1p = x + ((size_t)m1 * T_SZ + t) * D_SZ + qk;
        #pragma unroll
        for (int kk = 0; kk < 8; ++kk) {
            bf16x8 a0 = cvt8(x0p + kk * 32);
            bf16x8 a1 = cvt8(x1p + kk * 32);
            bf16x8 bb = *(const bf16x8*)(bp + (NKH + kk) * (COLS * 32));
            acc0 = __builtin_amdgcn_mfma_f32_16x16x32_bf16(a0, bb, acc0, 0, 0, 0);
            acc1 = __builtin_amdgcn_mfma_f32_16x16x32_bf16(a1, bb, acc1, 0, 0, 0);
        }

        // C/D layout (m89-verified): col = lane&15, row = (lane>>4)*4 + reg.
        {
            int rowb = wave * 32 + (lane >> 4) * 4;
            #pragma unroll
            for (int r = 0; r < 4; ++r) {
                G[(rowb + r) * COLS + cidx]      = acc0[r];
                G[(rowb + 16 + r) * COLS + cidx] = acc1[r];
            }
        }
        __syncthreads();

        // Elementwise LSTM cell: thread owns cells (bl, u0) and (bl, u0+1).
        const int wb = rb ^ 1;
        bf16_t* hdst = hbuf + wb * (B_SZ * H_SZ);
        float hv[2];
        #pragma unroll
        for (int s = 0; s < 2; ++s) {
            int u = u0 + s;
            float gi = G[bl * COLS + u]      + sbias[u];
            float gf = G[bl * COLS + 4 + u]  + sbias[4 + u];
            float gg = G[bl * COLS + 8 + u]  + sbias[8 + u];
            float go = G[bl * COLS + 12 + u] + sbias[12 + u];
            float i_ = 1.f / (1.f + __expf(-gi));
            float f_ = 1.f / (1.f + __expf(-gf));
            float g_ = tanhf(gg);
            float o_ = 1.f / (1.f + __expf(-go));
            float cn = f_ * (s ? c1 : c0) + i_ * g_;
            if (s) c1 = cn; else c0 = cn;
            hv[s] = o_ * tanhf(cn);
        }
        union { unsigned int u32; bf16_t h2[2]; } pk;
        pk.h2[0] = __float2bfloat16(hv[0]);
        pk.h2[1] = __float2bfloat16(hv[1]);
        // Write-through agent-scope store: lands at the coherence point, no
        // cache-maintenance op, exactly one 4B store per thread.
        __hip_atomic_store((unsigned int*)(hdst + bl * H_SZ + jg * 4 + u0), pk.u32,
                           __ATOMIC_RELAXED, __HIP_MEMORY_SCOPE_AGENT);

        if (t != T_SZ - 1) grid_barrier(flags, (unsigned int)t + 1u);
        // final h reaches memory via kernel-end writeback; decode is stream-ordered
    }
}

// out[128,10] = h_T @ Wd + bd. h_T (bf16) is in hbuf[0]; Wd/bd/out are fp32.
__global__ void decode(const bf16_t* __restrict__ h, const float* __restrict__ Wd,
                       const float* __restrict__ bd, float* __restrict__ out) {
    int b = blockIdx.x;
    int l = threadIdx.x;   // 64
    float acc[O_SZ] = {};
    for (int k = l; k < H_SZ; k += 64) {
        float hv = __bfloat162float(h[b * H_SZ + k]);
        #pragma unroll
        for (int o = 0; o < O_SZ; ++o)
            acc[o] += hv * Wd[k * O_SZ + o];
    }
    #pragma unroll
    for (int o = 0; o < O_SZ; ++o)
        #pragma unroll
        for (int off = 32; off; off >>= 1)
            acc[o] += __shfl_down(acc[o], off);
    if (l == 0)
        #pragma unroll
        for (int o = 0; o < O_SZ; ++o)
            out[b * O_SZ + o] = acc[o] + bd[o];
}

extern "C" void kernel_launch(void* const* d_in, const int* in_sizes, int n_in,
                              void* d_out, int out_size, void* d_ws, size_t ws_size,
                              hipStream_t stream) {
    const float* x  = (const float*)d_in[0];
    const float* Wx = (const float*)d_in[1];
    const float* Wh = (const float*)d_in[2];
    const float* bb = (const float*)d_in[3];
    const float* Wd = (const float*)d_in[4];
    const float* bd = (const float*)d_in[5];
    float* out = (float*)d_out;

    bf16_t* hbuf = (bf16_t*)d_ws;                         // [2][128][1024] = 512 KB
    unsigned int* flags = (unsigned int*)((char*)d_ws + 2 * B_SZ * H_SZ * sizeof(bf16_t));

    init_state<<<dim3(NWG), dim3(256), 0, stream>>>((unsigned int*)d_ws, flags);
    lstm_main<<<dim3(NWG), dim3(256), 0, stream>>>(x, Wx, Wh, bb, hbuf, flags);
    decode<<<dim3(B_SZ), dim3(64), 0, stream>>>(hbuf, Wd, bd, out);
}